// Round 3
// baseline (510.448 us; speedup 1.0000x reference)
//
#include <hip/hip_runtime.h>
#include <hip/hip_bf16.h>

#define FIN   128
#define NH    8
#define NEG   0.2f

typedef __attribute__((ext_vector_type(8))) short short8;   // 8 bf16 in 4 VGPRs
typedef __attribute__((ext_vector_type(4))) float f32x4;

// ---- dtype-adaptive load helpers (flags decided at runtime by k_detect) ----
__device__ __forceinline__ short f2bf(float f) {            // fp32 -> bf16 bits, RNE
    unsigned u = __float_as_uint(f);
    return (short)((u + 0x7FFFu + ((u >> 16) & 1u)) >> 16);
}
__device__ __forceinline__ float ld_f(const void* p, int i, bool bf16) {
    if (bf16) {
        unsigned h = ((const unsigned short*)p)[i];
        return __uint_as_float(h << 16);
    }
    return ((const float*)p)[i];
}
__device__ __forceinline__ short8 ld_frag(const void* p, size_t off, bool bf16) {
    if (bf16) return *(const short8*)((const short*)p + off);
    const float* f = (const float*)p + off;
    f32x4 f0 = *(const f32x4*)f;
    f32x4 f1 = *(const f32x4*)(f + 4);
    short8 r;
    r[0] = f2bf(f0[0]); r[1] = f2bf(f0[1]); r[2] = f2bf(f0[2]); r[3] = f2bf(f0[3]);
    r[4] = f2bf(f1[0]); r[5] = f2bf(f1[1]); r[6] = f2bf(f1[2]); r[7] = f2bf(f1[3]);
    return r;
}
__device__ __forceinline__ int ld_edge(const int* e, size_t i, bool e64) {
    return e64 ? e[2 * i] : e[i];   // little-endian, values < 2^31
}

// Kernel 0: probe input dtypes from bit patterns (deterministic for this data).
__global__ __launch_bounds__(64) void k_detect(const unsigned* __restrict__ x32,
                                               const int* __restrict__ e32,
                                               int* __restrict__ flags)
{
    int t = threadIdx.x;
    unsigned w  = x32[t];
    unsigned ex = (w >> 7) & 0xFFu;
    unsigned long long mb = __ballot(ex >= 118u && ex <= 130u);
    unsigned long long mz = __ballot(e32[2 * t + 1] == 0);
    if (t == 0) {
        flags[0] = (__popcll(mb) >= 48) ? 1 : 0;
        flags[1] = (__popcll(mz) == 64) ? 1 : 0;
    }
}

// Kernel 1: proj = x@Wp^T (blockIdx.y=0) or skip = x@Ws^T (blockIdx.y=1).
// One wave per 16 rows per matrix; fused per-node head scores on the proj path.
__global__ __launch_bounds__(64) void k_proj(
    const void* __restrict__ x, const void* __restrict__ Wp,
    const void* __restrict__ Ws,
    const void* __restrict__ ssrcw, const void* __restrict__ stgtw,
    float* __restrict__ proj, float* __restrict__ skip,
    float* __restrict__ s_src, float* __restrict__ s_tgt,
    const int* __restrict__ flags)
{
    const bool bf16 = flags[0] != 0;
    const int lane = threadIdx.x;
    const int m0 = blockIdx.x * 16;
    const int mat = blockIdx.y;
    const int mr = lane & 15;
    const int kb = lane >> 4;

    short8 a[4];
    const size_t xoff = (size_t)(m0 + mr) * FIN + kb * 8;
#pragma unroll
    for (int s = 0; s < 4; ++s) a[s] = ld_frag(x, xoff + s * 32, bf16);

    const void* W = mat ? Ws : Wp;
    f32x4 acc[8];
#pragma unroll
    for (int c = 0; c < 8; ++c) {
        acc[c] = (f32x4){0.f, 0.f, 0.f, 0.f};
        const size_t woff = (size_t)(c * 16 + mr) * FIN + kb * 8;
#pragma unroll
        for (int s = 0; s < 4; ++s) {
            short8 b = ld_frag(W, woff + s * 32, bf16);
            acc[c] = __builtin_amdgcn_mfma_f32_16x16x32_bf16(a[s], b, acc[c], 0, 0, 0);
        }
    }
    // D layout: col = lane&15, row = (lane>>4)*4 + r   [verified m89]
    if (mat == 0) {
#pragma unroll
        for (int c = 0; c < 8; ++c) {
            float sw = ld_f(ssrcw, c * 16 + mr, bf16);
            float tw = ld_f(stgtw, c * 16 + mr, bf16);
#pragma unroll
            for (int r = 0; r < 4; ++r) {
                int row = m0 + kb * 4 + r;
                float v = acc[c][r];
                proj[(size_t)row * FIN + c * 16 + mr] = v;
                float vs = v * sw, vt = v * tw;
#pragma unroll
                for (int o = 8; o >= 1; o >>= 1) {
                    vs += __shfl_xor(vs, o);
                    vt += __shfl_xor(vt, o);
                }
                if (mr == 0) {
                    s_src[row * NH + c] = vs;
                    s_tgt[row * NH + c] = vt;
                }
            }
        }
    } else {
#pragma unroll
        for (int c = 0; c < 8; ++c)
#pragma unroll
            for (int r = 0; r < 4; ++r)
                skip[(size_t)(m0 + kb * 4 + r) * FIN + c * 16 + mr] = acc[c][r];
    }
}

// Kernel 2: histogram of targets
__global__ __launch_bounds__(256) void k_hist(const int* __restrict__ edges,
                                              int* __restrict__ cnt, int E,
                                              const int* __restrict__ flags)
{
    const bool e64 = flags[1] != 0;
    int e = blockIdx.x * blockDim.x + threadIdx.x;
    if (e < E) atomicAdd(&cnt[ld_edge(edges, (size_t)E + e, e64)], 1);
}

// Kernel 3: single-block exclusive scan, 256 threads x 40 elems serial + one
// 256-wide block scan (16 barriers total, vs ~300 in the Hillis-Steele-by-chunk
// version this replaces).
__global__ __launch_bounds__(256) void k_scan(int* __restrict__ cnt,
                                              int* __restrict__ offs, int N)
{
    const int t = threadIdx.x;
    const int PER = (N + 255) / 256;          // 40 for N=10000
    const int base = t * PER;
    int local[40];                            // exclusive prefix within thread
    int sum = 0;
    for (int i = 0; i < PER && i < 40; ++i) {
        int idx = base + i;
        int v = (idx < N) ? cnt[idx] : 0;
        local[i] = sum;
        sum += v;
    }
    __shared__ int sd[256];
    sd[t] = sum;
    __syncthreads();
#pragma unroll
    for (int off = 1; off < 256; off <<= 1) {
        int add = (t >= off) ? sd[t - off] : 0;
        __syncthreads();
        sd[t] += add;
        __syncthreads();
    }
    int excl = sd[t] - sum;                   // exclusive across threads
    for (int i = 0; i < PER && i < 40; ++i) {
        int idx = base + i;
        if (idx < N) {
            int e = excl + local[i];
            offs[idx] = e;
            cnt[idx] = e;                     // cnt doubles as scatter cursor
        }
    }
    if (t == 255) offs[N] = sd[255];
}

// Kernel 4: scatter edges into tgt-sorted order; store EXP'd leaky-relu scores
// and atomically accumulate per-(node,head) softmax denominators.
__global__ __launch_bounds__(256) void k_scatter(
    const int* __restrict__ edges,
    const float* __restrict__ s_src, const float* __restrict__ s_tgt,
    int* __restrict__ cursor, int* __restrict__ sorted_src,
    float* __restrict__ score, float* __restrict__ denom,
    int E, const int* __restrict__ flags)
{
    const bool e64 = flags[1] != 0;
    int e = blockIdx.x * blockDim.x + threadIdx.x;
    if (e >= E) return;
    int s = ld_edge(edges, e, e64);
    int t = ld_edge(edges, (size_t)E + e, e64);
    int pos = atomicAdd(&cursor[t], 1);
    sorted_src[pos] = s;
    f32x4 a0 = *(const f32x4*)(s_src + (size_t)s * NH);
    f32x4 a1 = *(const f32x4*)(s_src + (size_t)s * NH + 4);
    f32x4 b0 = *(const f32x4*)(s_tgt + (size_t)t * NH);
    f32x4 b1 = *(const f32x4*)(s_tgt + (size_t)t * NH + 4);
    f32x4 o0, o1;
#pragma unroll
    for (int i = 0; i < 4; ++i) {
        float v0 = a0[i] + b0[i];
        float v1 = a1[i] + b1[i];
        v0 = v0 > 0.f ? v0 : NEG * v0;
        v1 = v1 > 0.f ? v1 : NEG * v1;
        o0[i] = __expf(fminf(v0, 60.f));
        o1[i] = __expf(fminf(v1, 60.f));
    }
    *(f32x4*)(score + (size_t)pos * NH) = o0;
    *(f32x4*)(score + (size_t)pos * NH + 4) = o1;
    float* dn = denom + (size_t)t * NH;
#pragma unroll
    for (int i = 0; i < 4; ++i) {
        atomicAdd(&dn[i], o0[i]);
        atomicAdd(&dn[i + 4], o1[i]);
    }
}

// Kernel 5: single-pass weighted aggregation + skip + bias. No LDS, no
// barriers; 4-way unrolled with independent accumulators for MLP.
// Thread t owns output column t (head t>>4, feat t&15).
__global__ __launch_bounds__(128) void k_aggregate(
    const int* __restrict__ offs, const int* __restrict__ sorted_src,
    const float* __restrict__ score, const float* __restrict__ proj,
    const float* __restrict__ skip, const void* __restrict__ bias,
    const float* __restrict__ denom, void* __restrict__ out,
    const int* __restrict__ flags)
{
    const bool bf16 = flags[0] != 0;
    const int n = blockIdx.x, t = threadIdx.x;
    const int start = offs[n], end = offs[n + 1];
    const int h = t >> 4;
    const float invd = 1.f / (denom[(size_t)n * NH + h] + 1e-16f);

    float ac0 = 0.f, ac1 = 0.f, ac2 = 0.f, ac3 = 0.f;
    int e = start;
    for (; e + 4 <= end; e += 4) {
        int s0 = sorted_src[e], s1 = sorted_src[e + 1];
        int s2 = sorted_src[e + 2], s3 = sorted_src[e + 3];
        float w0 = score[(size_t)e * NH + h];
        float w1 = score[(size_t)(e + 1) * NH + h];
        float w2 = score[(size_t)(e + 2) * NH + h];
        float w3 = score[(size_t)(e + 3) * NH + h];
        float p0 = proj[(size_t)s0 * FIN + t];
        float p1 = proj[(size_t)s1 * FIN + t];
        float p2 = proj[(size_t)s2 * FIN + t];
        float p3 = proj[(size_t)s3 * FIN + t];
        ac0 += w0 * p0; ac1 += w1 * p1; ac2 += w2 * p2; ac3 += w3 * p3;
    }
    for (; e < end; ++e)
        ac0 += score[(size_t)e * NH + h] * proj[(size_t)sorted_src[e] * FIN + t];

    float o = (ac0 + ac1 + ac2 + ac3) * invd
            + skip[(size_t)n * FIN + t] + ld_f(bias, t, bf16);
    if (bf16) ((__hip_bfloat16*)out)[(size_t)n * FIN + t] = __float2bfloat16(o);
    else      ((float*)out)[(size_t)n * FIN + t] = o;
}

extern "C" void kernel_launch(void* const* d_in, const int* in_sizes, int n_in,
                              void* d_out, int out_size, void* d_ws, size_t ws_size,
                              hipStream_t stream)
{
    const void* x    = d_in[0];
    const int* edges = (const int*)d_in[1];
    const void* Wp   = d_in[2];
    const void* Ws   = d_in[3];
    const void* ssw  = d_in[4];
    const void* stw  = d_in[5];
    const void* bias = d_in[6];

    const int N = in_sizes[0] / FIN;   // 10000
    const int E = in_sizes[1] / 2;     // 640000

    // workspace layout (fp32 elements)
    float* ws       = (float*)d_ws;
    float* proj     = ws;                               // N*128
    float* skip     = proj + (size_t)N * FIN;           // N*128
    float* s_src    = skip + (size_t)N * FIN;           // N*8
    float* s_tgt    = s_src + (size_t)N * NH;           // N*8
    float* score    = s_tgt + (size_t)N * NH;           // E*8
    int* sorted_src = (int*)(score + (size_t)E * NH);   // E
    int* offs       = sorted_src + E;                   // N+1
    int* cursor     = offs + (N + 1);                   // N
    float* denom    = (float*)(cursor + N);             // N*8 (zeroed w/ cursor)
    int* flags      = (int*)(denom + (size_t)N * NH);   // 2

    // zero cursor + denom in one contiguous memset
    hipMemsetAsync(cursor, 0, (size_t)N * 9 * sizeof(int), stream);

    k_detect<<<1, 64, 0, stream>>>((const unsigned*)x, edges, flags);
    dim3 pg((N + 15) / 16, 2);
    k_proj<<<pg, 64, 0, stream>>>(x, Wp, Ws, ssw, stw, proj, skip, s_src, s_tgt, flags);
    k_hist<<<(E + 255) / 256, 256, 0, stream>>>(edges, cursor, E, flags);
    k_scan<<<1, 256, 0, stream>>>(cursor, offs, N);
    k_scatter<<<(E + 255) / 256, 256, 0, stream>>>(edges, s_src, s_tgt, cursor,
                                                   sorted_src, score, denom, E, flags);
    k_aggregate<<<N, 128, 0, stream>>>(offs, sorted_src, score, proj, skip, bias,
                                       denom, d_out, flags);
}

// Round 4
// 243.417 us; speedup vs baseline: 2.0970x; 2.0970x over previous
//
#include <hip/hip_runtime.h>
#include <hip/hip_bf16.h>

#define FIN   128
#define NH    8
#define NEG   0.2f

typedef __attribute__((ext_vector_type(8))) short short8;   // 8 bf16 in 4 VGPRs
typedef __attribute__((ext_vector_type(4))) float f32x4;

// ---- dtype-adaptive load helpers (flags decided at runtime by k_detect) ----
__device__ __forceinline__ short f2bf(float f) {            // fp32 -> bf16 bits, RNE
    unsigned u = __float_as_uint(f);
    return (short)((u + 0x7FFFu + ((u >> 16) & 1u)) >> 16);
}
__device__ __forceinline__ float ld_f(const void* p, int i, bool bf16) {
    if (bf16) {
        unsigned h = ((const unsigned short*)p)[i];
        return __uint_as_float(h << 16);
    }
    return ((const float*)p)[i];
}
__device__ __forceinline__ short8 ld_frag(const void* p, size_t off, bool bf16) {
    if (bf16) return *(const short8*)((const short*)p + off);
    const float* f = (const float*)p + off;
    f32x4 f0 = *(const f32x4*)f;
    f32x4 f1 = *(const f32x4*)(f + 4);
    short8 r;
    r[0] = f2bf(f0[0]); r[1] = f2bf(f0[1]); r[2] = f2bf(f0[2]); r[3] = f2bf(f0[3]);
    r[4] = f2bf(f1[0]); r[5] = f2bf(f1[1]); r[6] = f2bf(f1[2]); r[7] = f2bf(f1[3]);
    return r;
}
__device__ __forceinline__ int ld_edge(const int* e, size_t i, bool e64) {
    return e64 ? e[2 * i] : e[i];   // little-endian, values < 2^31
}
__device__ __forceinline__ float escore(float ss, float st) {
    float v = ss + st;
    v = v > 0.f ? v : NEG * v;                // leaky relu
    return __expf(fminf(v, 60.f));            // shift-free softmax numerator
}

// Kernel 0: probe input dtypes from bit patterns (deterministic for this data).
__global__ __launch_bounds__(64) void k_detect(const unsigned* __restrict__ x32,
                                               const int* __restrict__ e32,
                                               int* __restrict__ flags)
{
    int t = threadIdx.x;
    unsigned w  = x32[t];
    unsigned ex = (w >> 7) & 0xFFu;
    unsigned long long mb = __ballot(ex >= 118u && ex <= 130u);
    unsigned long long mz = __ballot(e32[2 * t + 1] == 0);
    if (t == 0) {
        flags[0] = (__popcll(mb) >= 48) ? 1 : 0;
        flags[1] = (__popcll(mz) == 64) ? 1 : 0;
    }
}

// Kernel 1: proj = x@Wp^T (blockIdx.y=0) or skip = x@Ws^T (blockIdx.y=1).
// One wave per 16 rows per matrix; fused per-node head scores on the proj path.
__global__ __launch_bounds__(64) void k_proj(
    const void* __restrict__ x, const void* __restrict__ Wp,
    const void* __restrict__ Ws,
    const void* __restrict__ ssrcw, const void* __restrict__ stgtw,
    float* __restrict__ proj, float* __restrict__ skip,
    float* __restrict__ s_src, float* __restrict__ s_tgt,
    const int* __restrict__ flags)
{
    const bool bf16 = flags[0] != 0;
    const int lane = threadIdx.x;
    const int m0 = blockIdx.x * 16;
    const int mat = blockIdx.y;
    const int mr = lane & 15;
    const int kb = lane >> 4;

    short8 a[4];
    const size_t xoff = (size_t)(m0 + mr) * FIN + kb * 8;
#pragma unroll
    for (int s = 0; s < 4; ++s) a[s] = ld_frag(x, xoff + s * 32, bf16);

    const void* W = mat ? Ws : Wp;
    f32x4 acc[8];
#pragma unroll
    for (int c = 0; c < 8; ++c) {
        acc[c] = (f32x4){0.f, 0.f, 0.f, 0.f};
        const size_t woff = (size_t)(c * 16 + mr) * FIN + kb * 8;
#pragma unroll
        for (int s = 0; s < 4; ++s) {
            short8 b = ld_frag(W, woff + s * 32, bf16);
            acc[c] = __builtin_amdgcn_mfma_f32_16x16x32_bf16(a[s], b, acc[c], 0, 0, 0);
        }
    }
    // D layout: col = lane&15, row = (lane>>4)*4 + r   [verified m89]
    if (mat == 0) {
#pragma unroll
        for (int c = 0; c < 8; ++c) {
            float sw = ld_f(ssrcw, c * 16 + mr, bf16);
            float tw = ld_f(stgtw, c * 16 + mr, bf16);
#pragma unroll
            for (int r = 0; r < 4; ++r) {
                int row = m0 + kb * 4 + r;
                float v = acc[c][r];
                proj[(size_t)row * FIN + c * 16 + mr] = v;
                float vs = v * sw, vt = v * tw;
#pragma unroll
                for (int o = 8; o >= 1; o >>= 1) {
                    vs += __shfl_xor(vs, o);
                    vt += __shfl_xor(vt, o);
                }
                if (mr == 0) {
                    s_src[row * NH + c] = vs;
                    s_tgt[row * NH + c] = vt;
                }
            }
        }
    } else {
#pragma unroll
        for (int c = 0; c < 8; ++c)
#pragma unroll
            for (int r = 0; r < 4; ++r)
                skip[(size_t)(m0 + kb * 4 + r) * FIN + c * 16 + mr] = acc[c][r];
    }
}

// Kernel 2: histogram of targets
__global__ __launch_bounds__(256) void k_hist(const int* __restrict__ edges,
                                              int* __restrict__ cnt, int E,
                                              const int* __restrict__ flags)
{
    const bool e64 = flags[1] != 0;
    int e = blockIdx.x * blockDim.x + threadIdx.x;
    if (e < E) atomicAdd(&cnt[ld_edge(edges, (size_t)E + e, e64)], 1);
}

// Kernel 3: single-block exclusive scan, 256 threads x 40 elems serial + one
// 256-wide block scan (16 barriers total).
__global__ __launch_bounds__(256) void k_scan(int* __restrict__ cnt,
                                              int* __restrict__ offs, int N)
{
    const int t = threadIdx.x;
    const int PER = (N + 255) / 256;          // 40 for N=10000
    const int base = t * PER;
    int local[40];                            // exclusive prefix within thread
    int sum = 0;
    for (int i = 0; i < PER && i < 40; ++i) {
        int idx = base + i;
        int v = (idx < N) ? cnt[idx] : 0;
        local[i] = sum;
        sum += v;
    }
    __shared__ int sd[256];
    sd[t] = sum;
    __syncthreads();
#pragma unroll
    for (int off = 1; off < 256; off <<= 1) {
        int add = (t >= off) ? sd[t - off] : 0;
        __syncthreads();
        sd[t] += add;
        __syncthreads();
    }
    int excl = sd[t] - sum;                   // exclusive across threads
    for (int i = 0; i < PER && i < 40; ++i) {
        int idx = base + i;
        if (idx < N) {
            int e = excl + local[i];
            offs[idx] = e;
            cnt[idx] = e;                     // cnt doubles as scatter cursor
        }
    }
    if (t == 255) offs[N] = sd[255];
}

// Kernel 4: scatter edge SOURCE ids into tgt-sorted order. Nothing else —
// scores are recomputed on the fly in k_aggregate (s_src is a 320 KB
// L1/L2-resident table; materializing score[E][8] cost 20+ MB of scattered
// traffic, and the denom atomics in R3 cost 221 MB of HBM writes).
__global__ __launch_bounds__(256) void k_scatter(
    const int* __restrict__ edges, int* __restrict__ cursor,
    int* __restrict__ sorted_src, int E, const int* __restrict__ flags)
{
    const bool e64 = flags[1] != 0;
    int e = blockIdx.x * blockDim.x + threadIdx.x;
    if (e >= E) return;
    int s = ld_edge(edges, e, e64);
    int t = ld_edge(edges, (size_t)E + e, e64);
    int pos = atomicAdd(&cursor[t], 1);
    sorted_src[pos] = s;
}

// Kernel 5: fully-fused single pass: numerator AND denominator accumulate in
// registers (out = Σ w·p / (Σ w + eps)); skip + bias epilogue. No LDS, no
// barriers, no atomics. Thread t owns output column t (head t>>4, feat t&15).
// 4-way unroll = 4 independent gather chains for memory-level parallelism.
__global__ __launch_bounds__(128) void k_aggregate(
    const int* __restrict__ offs, const int* __restrict__ sorted_src,
    const float* __restrict__ s_src, const float* __restrict__ s_tgt,
    const float* __restrict__ proj, const float* __restrict__ skip,
    const void* __restrict__ bias, void* __restrict__ out,
    const int* __restrict__ flags)
{
    const bool bf16 = flags[0] != 0;
    const int n = blockIdx.x, t = threadIdx.x;
    const int start = offs[n], end = offs[n + 1];
    const int h = t >> 4;
    const float st = s_tgt[(size_t)n * NH + h];

    float ac0 = 0.f, ac1 = 0.f, ac2 = 0.f, ac3 = 0.f;
    float d0 = 0.f, d1 = 0.f, d2 = 0.f, d3 = 0.f;
    int e = start;
    for (; e + 4 <= end; e += 4) {
        int s0 = sorted_src[e], s1 = sorted_src[e + 1];
        int s2 = sorted_src[e + 2], s3 = sorted_src[e + 3];
        float w0 = escore(s_src[(size_t)s0 * NH + h], st);
        float w1 = escore(s_src[(size_t)s1 * NH + h], st);
        float w2 = escore(s_src[(size_t)s2 * NH + h], st);
        float w3 = escore(s_src[(size_t)s3 * NH + h], st);
        float p0 = proj[(size_t)s0 * FIN + t];
        float p1 = proj[(size_t)s1 * FIN + t];
        float p2 = proj[(size_t)s2 * FIN + t];
        float p3 = proj[(size_t)s3 * FIN + t];
        ac0 += w0 * p0; ac1 += w1 * p1; ac2 += w2 * p2; ac3 += w3 * p3;
        d0 += w0; d1 += w1; d2 += w2; d3 += w3;
    }
    for (; e < end; ++e) {
        int s = sorted_src[e];
        float w = escore(s_src[(size_t)s * NH + h], st);
        ac0 += w * proj[(size_t)s * FIN + t];
        d0 += w;
    }

    float num = (ac0 + ac1) + (ac2 + ac3);
    float den = (d0 + d1) + (d2 + d3);
    float o = num / (den + 1e-16f)
            + skip[(size_t)n * FIN + t] + ld_f(bias, t, bf16);
    if (bf16) ((__hip_bfloat16*)out)[(size_t)n * FIN + t] = __float2bfloat16(o);
    else      ((float*)out)[(size_t)n * FIN + t] = o;
}

extern "C" void kernel_launch(void* const* d_in, const int* in_sizes, int n_in,
                              void* d_out, int out_size, void* d_ws, size_t ws_size,
                              hipStream_t stream)
{
    const void* x    = d_in[0];
    const int* edges = (const int*)d_in[1];
    const void* Wp   = d_in[2];
    const void* Ws   = d_in[3];
    const void* ssw  = d_in[4];
    const void* stw  = d_in[5];
    const void* bias = d_in[6];

    const int N = in_sizes[0] / FIN;   // 10000
    const int E = in_sizes[1] / 2;     // 640000

    // workspace layout (fp32/int32 elements)
    float* ws       = (float*)d_ws;
    float* proj     = ws;                               // N*128
    float* skip     = proj + (size_t)N * FIN;           // N*128
    float* s_src    = skip + (size_t)N * FIN;           // N*8
    float* s_tgt    = s_src + (size_t)N * NH;           // N*8
    int* sorted_src = (int*)(s_tgt + (size_t)N * NH);   // E
    int* offs       = sorted_src + E;                   // N+1
    int* cursor     = offs + (N + 1);                   // N
    int* flags      = cursor + N;                       // 2

    hipMemsetAsync(cursor, 0, (size_t)N * sizeof(int), stream);

    k_detect<<<1, 64, 0, stream>>>((const unsigned*)x, edges, flags);
    dim3 pg((N + 15) / 16, 2);
    k_proj<<<pg, 64, 0, stream>>>(x, Wp, Ws, ssw, stw, proj, skip, s_src, s_tgt, flags);
    k_hist<<<(E + 255) / 256, 256, 0, stream>>>(edges, cursor, E, flags);
    k_scan<<<1, 256, 0, stream>>>(cursor, offs, N);
    k_scatter<<<(E + 255) / 256, 256, 0, stream>>>(edges, cursor, sorted_src, E, flags);
    k_aggregate<<<N, 128, 0, stream>>>(offs, sorted_src, s_src, s_tgt, proj, skip,
                                       bias, d_out, flags);
}

// Round 5
// 228.337 us; speedup vs baseline: 2.2355x; 1.0660x over previous
//
#include <hip/hip_runtime.h>
#include <hip/hip_bf16.h>

#define FIN   128
#define NH    8
#define NEG   0.2f

typedef __attribute__((ext_vector_type(8))) short short8;   // 8 bf16 in 4 VGPRs
typedef __attribute__((ext_vector_type(4))) float f32x4;

// ---- helpers ----
__device__ __forceinline__ short f2bf(float f) {            // fp32 -> bf16 bits, RNE
    unsigned u = __float_as_uint(f);
    return (short)((u + 0x7FFFu + ((u >> 16) & 1u)) >> 16);
}
__device__ __forceinline__ float bflo(unsigned p) { return __uint_as_float(p << 16); }
__device__ __forceinline__ float bfhi(unsigned p) { return __uint_as_float(p & 0xFFFF0000u); }
__device__ __forceinline__ float ld_f(const void* p, int i, bool bf16) {
    if (bf16) {
        unsigned h = ((const unsigned short*)p)[i];
        return __uint_as_float(h << 16);
    }
    return ((const float*)p)[i];
}
__device__ __forceinline__ short8 ld_frag(const void* p, size_t off, bool bf16) {
    if (bf16) return *(const short8*)((const short*)p + off);
    const float* f = (const float*)p + off;
    f32x4 f0 = *(const f32x4*)f;
    f32x4 f1 = *(const f32x4*)(f + 4);
    short8 r;
    r[0] = f2bf(f0[0]); r[1] = f2bf(f0[1]); r[2] = f2bf(f0[2]); r[3] = f2bf(f0[3]);
    r[4] = f2bf(f1[0]); r[5] = f2bf(f1[1]); r[6] = f2bf(f1[2]); r[7] = f2bf(f1[3]);
    return r;
}
__device__ __forceinline__ float escore(float ss, float st) {
    float v = ss + st;
    v = v > 0.f ? v : NEG * v;                // leaky relu
    return __expf(fminf(v, 60.f));            // shift-free softmax numerator
}
// Per-wave dtype probes (replace the k_detect dispatch). All 64 lanes active.
__device__ __forceinline__ bool wave_bf16(const unsigned* x32) {
    unsigned w  = x32[threadIdx.x & 63];
    unsigned ex = (w >> 7) & 0xFFu;           // bf16 exponent of x[2*lane] if packed
    return __popcll(__ballot(ex >= 118u && ex <= 130u)) >= 48;
}
__device__ __forceinline__ bool wave_e64(const int* e32) {
    return __popcll(__ballot(e32[2 * (threadIdx.x & 63) + 1] == 0)) == 64;
}

// Kernel 1 (fused): blocks [0,projBlocks) do the two GEMMs (proj -> bf16 +
// fused head scores; skip -> fp32); blocks [projBlocks, ...) histogram tgt.
// Proj role: wave-tile wt in [0, tiles); wt < halfTiles => Wp, else Ws.
__global__ __launch_bounds__(256) void k_projhist(
    const void* __restrict__ x, const void* __restrict__ Wp,
    const void* __restrict__ Ws,
    const void* __restrict__ ssrcw, const void* __restrict__ stgtw,
    unsigned short* __restrict__ projb, float* __restrict__ skip,
    float* __restrict__ s_src, float* __restrict__ s_tgt,
    const int* __restrict__ e32, int* __restrict__ cnt,
    int E, int tiles, int halfTiles, int projBlocks)
{
    if ((int)blockIdx.x >= projBlocks) {
        // ---- histogram role ----
        const bool e64 = wave_e64(e32);
        int e = ((int)blockIdx.x - projBlocks) * 256 + threadIdx.x;
        if (e < E) {
            int t = e64 ? e32[2 * ((size_t)E + e)] : e32[(size_t)E + e];
            atomicAdd(&cnt[t], 1);
        }
        return;
    }
    // ---- GEMM role ----
    const bool bf16 = wave_bf16((const unsigned*)x);
    const int lane = threadIdx.x & 63;
    const int wt = blockIdx.x * 4 + (threadIdx.x >> 6);
    if (wt >= tiles) return;
    const int mat = (wt >= halfTiles) ? 1 : 0;
    const int m0 = (mat ? wt - halfTiles : wt) * 16;
    const int mr = lane & 15;
    const int kb = lane >> 4;

    short8 a[4];
    const size_t xoff = (size_t)(m0 + mr) * FIN + kb * 8;
#pragma unroll
    for (int s = 0; s < 4; ++s) a[s] = ld_frag(x, xoff + s * 32, bf16);

    const void* W = mat ? Ws : Wp;
    f32x4 acc[8];
#pragma unroll
    for (int c = 0; c < 8; ++c) {
        acc[c] = (f32x4){0.f, 0.f, 0.f, 0.f};
        const size_t woff = (size_t)(c * 16 + mr) * FIN + kb * 8;
#pragma unroll
        for (int s = 0; s < 4; ++s) {
            short8 b = ld_frag(W, woff + s * 32, bf16);
            acc[c] = __builtin_amdgcn_mfma_f32_16x16x32_bf16(a[s], b, acc[c], 0, 0, 0);
        }
    }
    // D layout: col = lane&15, row = (lane>>4)*4 + r   [verified m89]
    if (mat == 0) {
#pragma unroll
        for (int c = 0; c < 8; ++c) {
            float sw = ld_f(ssrcw, c * 16 + mr, bf16);
            float tw = ld_f(stgtw, c * 16 + mr, bf16);
#pragma unroll
            for (int r = 0; r < 4; ++r) {
                int row = m0 + kb * 4 + r;
                float v = acc[c][r];
                projb[(size_t)row * FIN + c * 16 + mr] = (unsigned short)f2bf(v);
                float vs = v * sw, vt = v * tw;
#pragma unroll
                for (int o = 8; o >= 1; o >>= 1) {
                    vs += __shfl_xor(vs, o);
                    vt += __shfl_xor(vt, o);
                }
                if (mr == 0) {
                    s_src[row * NH + c] = vs;
                    s_tgt[row * NH + c] = vt;
                }
            }
        }
    } else {
#pragma unroll
        for (int c = 0; c < 8; ++c)
#pragma unroll
            for (int r = 0; r < 4; ++r)
                skip[(size_t)(m0 + kb * 4 + r) * FIN + c * 16 + mr] = acc[c][r];
    }
}

// Kernel 2: single-block exclusive scan, 256 threads x ceil(N/256) serial +
// one 256-wide block scan (16 barriers total).
__global__ __launch_bounds__(256) void k_scan(int* __restrict__ cnt,
                                              int* __restrict__ offs, int N)
{
    const int t = threadIdx.x;
    const int PER = (N + 255) / 256;          // 40 for N=10000
    const int base = t * PER;
    int local[40];
    int sum = 0;
    for (int i = 0; i < PER && i < 40; ++i) {
        int idx = base + i;
        int v = (idx < N) ? cnt[idx] : 0;
        local[i] = sum;
        sum += v;
    }
    __shared__ int sd[256];
    sd[t] = sum;
    __syncthreads();
#pragma unroll
    for (int off = 1; off < 256; off <<= 1) {
        int add = (t >= off) ? sd[t - off] : 0;
        __syncthreads();
        sd[t] += add;
        __syncthreads();
    }
    int excl = sd[t] - sum;
    for (int i = 0; i < PER && i < 40; ++i) {
        int idx = base + i;
        if (idx < N) {
            int e = excl + local[i];
            offs[idx] = e;
            cnt[idx] = e;                     // cnt doubles as scatter cursor
        }
    }
    if (t == 255) offs[N] = sd[255];
}

// Kernel 3: scatter edge SOURCE ids into tgt-sorted order.
__global__ __launch_bounds__(256) void k_scatter(
    const int* __restrict__ e32, int* __restrict__ cursor,
    int* __restrict__ sorted_src, int E)
{
    const bool e64 = wave_e64(e32);
    int e = blockIdx.x * 256 + threadIdx.x;
    if (e >= E) return;
    int s = e64 ? e32[2 * (size_t)e]       : e32[e];
    int t = e64 ? e32[2 * ((size_t)E + e)] : e32[(size_t)E + e];
    int pos = atomicAdd(&cursor[t], 1);
    sorted_src[pos] = s;
}

// Kernel 4: one WAVE per node. Lane l owns column pair (2l, 2l+1) — both in
// head l>>3 — gathered as ONE packed bf16x2 4B load per edge. Numerator and
// denominator accumulate in registers; skip+bias epilogue. 4-way unroll =
// 4 independent gather chains.
__global__ __launch_bounds__(64) void k_aggregate(
    const int* __restrict__ offs, const int* __restrict__ sorted_src,
    const float* __restrict__ s_src, const float* __restrict__ s_tgt,
    const unsigned short* __restrict__ projb, const float* __restrict__ skip,
    const void* __restrict__ bias, void* __restrict__ out,
    const unsigned* __restrict__ x32)
{
    const bool bf16 = wave_bf16(x32);
    const int n = blockIdx.x, l = threadIdx.x;
    const int start = offs[n], end = offs[n + 1];
    const int h = l >> 3;
    const int c2 = l * 2;
    const float st = s_tgt[(size_t)n * NH + h];

    float ae0 = 0.f, ao0 = 0.f, ae1 = 0.f, ao1 = 0.f;
    float ae2 = 0.f, ao2 = 0.f, ae3 = 0.f, ao3 = 0.f;
    float d0 = 0.f, d1 = 0.f, d2 = 0.f, d3 = 0.f;
    int e = start;
    for (; e + 4 <= end; e += 4) {
        int s0 = sorted_src[e],     s1 = sorted_src[e + 1];
        int s2 = sorted_src[e + 2], s3 = sorted_src[e + 3];
        float w0 = escore(s_src[(size_t)s0 * NH + h], st);
        float w1 = escore(s_src[(size_t)s1 * NH + h], st);
        float w2 = escore(s_src[(size_t)s2 * NH + h], st);
        float w3 = escore(s_src[(size_t)s3 * NH + h], st);
        unsigned p0 = *(const unsigned*)(projb + (size_t)s0 * FIN + c2);
        unsigned p1 = *(const unsigned*)(projb + (size_t)s1 * FIN + c2);
        unsigned p2 = *(const unsigned*)(projb + (size_t)s2 * FIN + c2);
        unsigned p3 = *(const unsigned*)(projb + (size_t)s3 * FIN + c2);
        ae0 += w0 * bflo(p0); ao0 += w0 * bfhi(p0); d0 += w0;
        ae1 += w1 * bflo(p1); ao1 += w1 * bfhi(p1); d1 += w1;
        ae2 += w2 * bflo(p2); ao2 += w2 * bfhi(p2); d2 += w2;
        ae3 += w3 * bflo(p3); ao3 += w3 * bfhi(p3); d3 += w3;
    }
    for (; e < end; ++e) {
        int s = sorted_src[e];
        float w = escore(s_src[(size_t)s * NH + h], st);
        unsigned p = *(const unsigned*)(projb + (size_t)s * FIN + c2);
        ae0 += w * bflo(p); ao0 += w * bfhi(p); d0 += w;
    }

    float inv = 1.f / (((d0 + d1) + (d2 + d3)) + 1e-16f);
    float2 sk = *(const float2*)(skip + (size_t)n * FIN + c2);
    float be, bo;
    if (bf16) {
        unsigned bb = *(const unsigned*)((const unsigned short*)bias + c2);
        be = bflo(bb); bo = bfhi(bb);
    } else {
        float2 b2 = *(const float2*)((const float*)bias + c2);
        be = b2.x; bo = b2.y;
    }
    float oe = ((ae0 + ae1) + (ae2 + ae3)) * inv + sk.x + be;
    float oo = ((ao0 + ao1) + (ao2 + ao3)) * inv + sk.y + bo;
    if (bf16) {
        unsigned pr = ((unsigned)(unsigned short)f2bf(oo) << 16)
                    | (unsigned)(unsigned short)f2bf(oe);
        ((unsigned*)out)[((size_t)n * FIN + c2) >> 1] = pr;
    } else {
        float2 o2; o2.x = oe; o2.y = oo;
        *(float2*)((float*)out + (size_t)n * FIN + c2) = o2;
    }
}

extern "C" void kernel_launch(void* const* d_in, const int* in_sizes, int n_in,
                              void* d_out, int out_size, void* d_ws, size_t ws_size,
                              hipStream_t stream)
{
    const void* x    = d_in[0];
    const int* edges = (const int*)d_in[1];
    const void* Wp   = d_in[2];
    const void* Ws   = d_in[3];
    const void* ssw  = d_in[4];
    const void* stw  = d_in[5];
    const void* bias = d_in[6];

    const int N = in_sizes[0] / FIN;   // 10000
    const int E = in_sizes[1] / 2;     // 640000

    // workspace layout
    unsigned short* projb = (unsigned short*)d_ws;            // N*128 bf16
    float* skip     = (float*)(projb + (size_t)N * FIN);      // N*128 f32
    float* s_src    = skip + (size_t)N * FIN;                 // N*8
    float* s_tgt    = s_src + (size_t)N * NH;                 // N*8
    int* sorted_src = (int*)(s_tgt + (size_t)N * NH);         // E
    int* offs       = sorted_src + E;                         // N+1
    int* cursor     = offs + (N + 1);                         // N

    hipMemsetAsync(cursor, 0, (size_t)N * sizeof(int), stream);

    const int halfTiles  = (N + 15) / 16;        // 625
    const int tiles      = 2 * halfTiles;        // 1250
    const int projBlocks = (tiles + 3) / 4;      // 313
    const int histBlocks = (E + 255) / 256;      // 2500

    k_projhist<<<projBlocks + histBlocks, 256, 0, stream>>>(
        x, Wp, Ws, ssw, stw, projb, skip, s_src, s_tgt,
        edges, cursor, E, tiles, halfTiles, projBlocks);
    k_scan<<<1, 256, 0, stream>>>(cursor, offs, N);
    k_scatter<<<histBlocks, 256, 0, stream>>>(edges, cursor, sorted_src, E);
    k_aggregate<<<N, 64, 0, stream>>>(offs, sorted_src, s_src, s_tgt, projb,
                                      skip, bias, d_out, (const unsigned*)x);
}

// Round 6
// 166.934 us; speedup vs baseline: 3.0578x; 1.3678x over previous
//
#include <hip/hip_runtime.h>
#include <hip/hip_bf16.h>

#define FIN   128
#define NH    8
#define NEG   0.2f
#define HB    64          // fat histogram/placement blocks
#define NMAX  10240       // LDS histogram capacity (40 KB)

typedef __attribute__((ext_vector_type(8))) short short8;   // 8 bf16 in 4 VGPRs
typedef __attribute__((ext_vector_type(4))) float f32x4;

// ---- helpers ----
__device__ __forceinline__ short f2bf(float f) {            // fp32 -> bf16 bits, RNE
    unsigned u = __float_as_uint(f);
    return (short)((u + 0x7FFFu + ((u >> 16) & 1u)) >> 16);
}
__device__ __forceinline__ float bflo(unsigned p) { return __uint_as_float(p << 16); }
__device__ __forceinline__ float bfhi(unsigned p) { return __uint_as_float(p & 0xFFFF0000u); }
__device__ __forceinline__ float ld_f(const void* p, int i, bool bf16) {
    if (bf16) {
        unsigned h = ((const unsigned short*)p)[i];
        return __uint_as_float(h << 16);
    }
    return ((const float*)p)[i];
}
__device__ __forceinline__ short8 ld_frag(const void* p, size_t off, bool bf16) {
    if (bf16) return *(const short8*)((const short*)p + off);
    const float* f = (const float*)p + off;
    f32x4 f0 = *(const f32x4*)f;
    f32x4 f1 = *(const f32x4*)(f + 4);
    short8 r;
    r[0] = f2bf(f0[0]); r[1] = f2bf(f0[1]); r[2] = f2bf(f0[2]); r[3] = f2bf(f0[3]);
    r[4] = f2bf(f1[0]); r[5] = f2bf(f1[1]); r[6] = f2bf(f1[2]); r[7] = f2bf(f1[3]);
    return r;
}
__device__ __forceinline__ float escore(float ss, float st) {
    float v = ss + st;
    v = v > 0.f ? v : NEG * v;                // leaky relu
    return __expf(fminf(v, 60.f));            // shift-free softmax numerator
}
// Per-wave dtype probes. All 64 lanes active when called.
__device__ __forceinline__ bool wave_bf16(const unsigned* x32) {
    unsigned w  = x32[threadIdx.x & 63];
    unsigned ex = (w >> 7) & 0xFFu;           // bf16 exponent of x[2*lane] if packed
    return __popcll(__ballot(ex >= 118u && ex <= 130u)) >= 48;
}
__device__ __forceinline__ bool wave_e64(const int* e32) {
    return __popcll(__ballot(e32[2 * (threadIdx.x & 63) + 1] == 0)) == 64;
}

// Kernel 1 (fused): blocks [0,projBlocks) = the two GEMMs (proj->bf16 + fused
// head scores; skip->fp32). Blocks [projBlocks, projBlocks+HB) = per-block
// LDS histogram of tgt, written non-atomically to hist2d[b][*].
__global__ __launch_bounds__(256) void k_projhist(
    const void* __restrict__ x, const void* __restrict__ Wp,
    const void* __restrict__ Ws,
    const void* __restrict__ ssrcw, const void* __restrict__ stgtw,
    unsigned short* __restrict__ projb, float* __restrict__ skip,
    float* __restrict__ s_src, float* __restrict__ s_tgt,
    const int* __restrict__ e32, int* __restrict__ hist2d,
    int N, int E, int tiles, int halfTiles, int projBlocks, int perB)
{
    __shared__ int lhist[NMAX];
    if ((int)blockIdx.x >= projBlocks) {
        // ---- LDS histogram role (no global atomics) ----
        const bool e64 = wave_e64(e32);
        const int hb = (int)blockIdx.x - projBlocks;
        const int t = threadIdx.x;
        for (int j = t; j < N; j += 256) lhist[j] = 0;
        __syncthreads();
        const int lo = hb * perB;
        const int hi = min(lo + perB, E);
        for (int i = lo + t; i < hi; i += 256) {
            int tg = e64 ? e32[2 * ((size_t)E + i)] : e32[(size_t)E + i];
            atomicAdd(&lhist[tg], 1);          // LDS atomic
        }
        __syncthreads();
        for (int j = t; j < N; j += 256) hist2d[(size_t)hb * N + j] = lhist[j];
        return;
    }
    // ---- GEMM role ----
    const bool bf16 = wave_bf16((const unsigned*)x);
    const int lane = threadIdx.x & 63;
    const int wt = blockIdx.x * 4 + (threadIdx.x >> 6);
    if (wt >= tiles) return;
    const int mat = (wt >= halfTiles) ? 1 : 0;
    const int m0 = (mat ? wt - halfTiles : wt) * 16;
    const int mr = lane & 15;
    const int kb = lane >> 4;

    short8 a[4];
    const size_t xoff = (size_t)(m0 + mr) * FIN + kb * 8;
#pragma unroll
    for (int s = 0; s < 4; ++s) a[s] = ld_frag(x, xoff + s * 32, bf16);

    const void* W = mat ? Ws : Wp;
    f32x4 acc[8];
#pragma unroll
    for (int c = 0; c < 8; ++c) {
        acc[c] = (f32x4){0.f, 0.f, 0.f, 0.f};
        const size_t woff = (size_t)(c * 16 + mr) * FIN + kb * 8;
#pragma unroll
        for (int s = 0; s < 4; ++s) {
            short8 b = ld_frag(W, woff + s * 32, bf16);
            acc[c] = __builtin_amdgcn_mfma_f32_16x16x32_bf16(a[s], b, acc[c], 0, 0, 0);
        }
    }
    // D layout: col = lane&15, row = (lane>>4)*4 + r   [verified m89]
    if (mat == 0) {
#pragma unroll
        for (int c = 0; c < 8; ++c) {
            float sw = ld_f(ssrcw, c * 16 + mr, bf16);
            float tw = ld_f(stgtw, c * 16 + mr, bf16);
#pragma unroll
            for (int r = 0; r < 4; ++r) {
                int row = m0 + kb * 4 + r;
                float v = acc[c][r];
                projb[(size_t)row * FIN + c * 16 + mr] = (unsigned short)f2bf(v);
                float vs = v * sw, vt = v * tw;
#pragma unroll
                for (int o = 8; o >= 1; o >>= 1) {
                    vs += __shfl_xor(vs, o);
                    vt += __shfl_xor(vt, o);
                }
                if (mr == 0) {
                    s_src[row * NH + c] = vs;
                    s_tgt[row * NH + c] = vt;
                }
            }
        }
    } else {
#pragma unroll
        for (int c = 0; c < 8; ++c)
#pragma unroll
            for (int r = 0; r < 4; ++r)
                skip[(size_t)(m0 + kb * 4 + r) * FIN + c * 16 + mr] = acc[c][r];
    }
}

// Kernel 2: per-bin exclusive prefix across the HB block-rows (coalesced:
// thread <-> bin). pbase[b][j] = sum_{b'<b} hist2d[b'][j]; cnt[j] = total.
__global__ __launch_bounds__(256) void k_colscan(
    const int* __restrict__ hist2d, int* __restrict__ pbase,
    int* __restrict__ cnt, int N)
{
    int j = blockIdx.x * 256 + threadIdx.x;
    if (j >= N) return;
    int s = 0;
#pragma unroll 4
    for (int b = 0; b < HB; ++b) {
        int v = hist2d[(size_t)b * N + j];
        pbase[(size_t)b * N + j] = s;
        s += v;
    }
    cnt[j] = s;
}

// Kernel 3: single-block exclusive scan of cnt -> offs.
__global__ __launch_bounds__(256) void k_offscan(const int* __restrict__ cnt,
                                                 int* __restrict__ offs, int N)
{
    const int t = threadIdx.x;
    const int PER = (N + 255) / 256;          // 40 for N=10000
    const int base = t * PER;
    int local[40];
    int sum = 0;
    for (int i = 0; i < PER && i < 40; ++i) {
        int idx = base + i;
        int v = (idx < N) ? cnt[idx] : 0;
        local[i] = sum;
        sum += v;
    }
    __shared__ int sd[256];
    sd[t] = sum;
    __syncthreads();
#pragma unroll
    for (int off = 1; off < 256; off <<= 1) {
        int add = (t >= off) ? sd[t - off] : 0;
        __syncthreads();
        sd[t] += add;
        __syncthreads();
    }
    int excl = sd[t] - sum;
    for (int i = 0; i < PER && i < 40; ++i) {
        int idx = base + i;
        if (idx < N) offs[idx] = excl + local[i];
    }
    if (t == 255) offs[N] = sd[255];
}

// Kernel 4: placement. Block b re-reads its edge slice; LDS cursor seeded from
// offs+pbase; rank via LDS atomicAdd; one scattered 4B store per edge.
// Zero global atomics.
__global__ __launch_bounds__(256) void k_place(
    const int* __restrict__ e32, const int* __restrict__ offs,
    const int* __restrict__ pbase, int* __restrict__ sorted_src,
    int N, int E, int perB)
{
    __shared__ int cur[NMAX];
    const bool e64 = wave_e64(e32);
    const int b = blockIdx.x, t = threadIdx.x;
    for (int j = t; j < N; j += 256)
        cur[j] = offs[j] + pbase[(size_t)b * N + j];
    __syncthreads();
    const int lo = b * perB;
    const int hi = min(lo + perB, E);
    for (int i = lo + t; i < hi; i += 256) {
        int s, tg;
        if (e64) { s = e32[2 * (size_t)i]; tg = e32[2 * ((size_t)E + i)]; }
        else     { s = e32[i];             tg = e32[(size_t)E + i]; }
        int pos = atomicAdd(&cur[tg], 1);  // LDS atomic
        sorted_src[pos] = s;
    }
}

// Kernel 5: one WAVE per node. Lane l owns column pair (2l, 2l+1) — both in
// head l>>3 — gathered as ONE packed bf16x2 4B load per edge. Numerator and
// denominator accumulate in registers; skip+bias epilogue. 4-way unroll.
__global__ __launch_bounds__(64) void k_aggregate(
    const int* __restrict__ offs, const int* __restrict__ sorted_src,
    const float* __restrict__ s_src, const float* __restrict__ s_tgt,
    const unsigned short* __restrict__ projb, const float* __restrict__ skip,
    const void* __restrict__ bias, void* __restrict__ out,
    const unsigned* __restrict__ x32)
{
    const bool bf16 = wave_bf16(x32);
    const int n = blockIdx.x, l = threadIdx.x;
    const int start = offs[n], end = offs[n + 1];
    const int h = l >> 3;
    const int c2 = l * 2;
    const float st = s_tgt[(size_t)n * NH + h];

    float ae0 = 0.f, ao0 = 0.f, ae1 = 0.f, ao1 = 0.f;
    float ae2 = 0.f, ao2 = 0.f, ae3 = 0.f, ao3 = 0.f;
    float d0 = 0.f, d1 = 0.f, d2 = 0.f, d3 = 0.f;
    int e = start;
    for (; e + 4 <= end; e += 4) {
        int s0 = sorted_src[e],     s1 = sorted_src[e + 1];
        int s2 = sorted_src[e + 2], s3 = sorted_src[e + 3];
        float w0 = escore(s_src[(size_t)s0 * NH + h], st);
        float w1 = escore(s_src[(size_t)s1 * NH + h], st);
        float w2 = escore(s_src[(size_t)s2 * NH + h], st);
        float w3 = escore(s_src[(size_t)s3 * NH + h], st);
        unsigned p0 = *(const unsigned*)(projb + (size_t)s0 * FIN + c2);
        unsigned p1 = *(const unsigned*)(projb + (size_t)s1 * FIN + c2);
        unsigned p2 = *(const unsigned*)(projb + (size_t)s2 * FIN + c2);
        unsigned p3 = *(const unsigned*)(projb + (size_t)s3 * FIN + c2);
        ae0 += w0 * bflo(p0); ao0 += w0 * bfhi(p0); d0 += w0;
        ae1 += w1 * bflo(p1); ao1 += w1 * bfhi(p1); d1 += w1;
        ae2 += w2 * bflo(p2); ao2 += w2 * bfhi(p2); d2 += w2;
        ae3 += w3 * bflo(p3); ao3 += w3 * bfhi(p3); d3 += w3;
    }
    for (; e < end; ++e) {
        int s = sorted_src[e];
        float w = escore(s_src[(size_t)s * NH + h], st);
        unsigned p = *(const unsigned*)(projb + (size_t)s * FIN + c2);
        ae0 += w * bflo(p); ao0 += w * bfhi(p); d0 += w;
    }

    float inv = 1.f / (((d0 + d1) + (d2 + d3)) + 1e-16f);
    float2 sk = *(const float2*)(skip + (size_t)n * FIN + c2);
    float be, bo;
    if (bf16) {
        unsigned bb = *(const unsigned*)((const unsigned short*)bias + c2);
        be = bflo(bb); bo = bfhi(bb);
    } else {
        float2 b2 = *(const float2*)((const float*)bias + c2);
        be = b2.x; bo = b2.y;
    }
    float oe = ((ae0 + ae1) + (ae2 + ae3)) * inv + sk.x + be;
    float oo = ((ao0 + ao1) + (ao2 + ao3)) * inv + sk.y + bo;
    if (bf16) {
        unsigned pr = ((unsigned)(unsigned short)f2bf(oo) << 16)
                    | (unsigned)(unsigned short)f2bf(oe);
        ((unsigned*)out)[((size_t)n * FIN + c2) >> 1] = pr;
    } else {
        float2 o2; o2.x = oe; o2.y = oo;
        *(float2*)((float*)out + (size_t)n * FIN + c2) = o2;
    }
}

extern "C" void kernel_launch(void* const* d_in, const int* in_sizes, int n_in,
                              void* d_out, int out_size, void* d_ws, size_t ws_size,
                              hipStream_t stream)
{
    const void* x    = d_in[0];
    const int* edges = (const int*)d_in[1];
    const void* Wp   = d_in[2];
    const void* Ws   = d_in[3];
    const void* ssw  = d_in[4];
    const void* stw  = d_in[5];
    const void* bias = d_in[6];

    const int N = in_sizes[0] / FIN;   // 10000
    const int E = in_sizes[1] / 2;     // 640000

    // workspace layout
    unsigned short* projb = (unsigned short*)d_ws;            // N*128 bf16
    float* skip     = (float*)(projb + (size_t)N * FIN);      // N*128 f32
    float* s_src    = skip + (size_t)N * FIN;                 // N*8
    float* s_tgt    = s_src + (size_t)N * NH;                 // N*8
    int* sorted_src = (int*)(s_tgt + (size_t)N * NH);         // E
    int* offs       = sorted_src + E;                         // N+1
    int* cnt        = offs + (N + 1);                         // N
    int* hist2d     = cnt + N;                                // HB*N
    int* pbase      = hist2d + (size_t)HB * N;                // HB*N

    const int halfTiles  = (N + 15) / 16;        // 625
    const int tiles      = 2 * halfTiles;        // 1250
    const int projBlocks = (tiles + 3) / 4;      // 313
    const int perB       = (E + HB - 1) / HB;    // 10000

    k_projhist<<<projBlocks + HB, 256, 0, stream>>>(
        x, Wp, Ws, ssw, stw, projb, skip, s_src, s_tgt,
        edges, hist2d, N, E, tiles, halfTiles, projBlocks, perB);
    k_colscan<<<(N + 255) / 256, 256, 0, stream>>>(hist2d, pbase, cnt, N);
    k_offscan<<<1, 256, 0, stream>>>(cnt, offs, N);
    k_place<<<HB, 256, 0, stream>>>(edges, offs, pbase, sorted_src, N, E, perB);
    k_aggregate<<<N, 64, 0, stream>>>(offs, sorted_src, s_src, s_tgt, projb,
                                      skip, bias, d_out, (const unsigned*)x);
}

// Round 7
// 165.897 us; speedup vs baseline: 3.0769x; 1.0063x over previous
//
#include <hip/hip_runtime.h>
#include <hip/hip_bf16.h>

#define FIN   128
#define NH    8
#define NEG   0.2f
#define HB    128         // histogram/placement blocks
#define NMAX  10240       // LDS cursor capacity (40 KB in k_place)

typedef __attribute__((ext_vector_type(8))) short short8;   // 8 bf16 in 4 VGPRs
typedef __attribute__((ext_vector_type(4))) float f32x4;

// ---- helpers ----
__device__ __forceinline__ short f2bf(float f) {            // fp32 -> bf16 bits, RNE
    unsigned u = __float_as_uint(f);
    return (short)((u + 0x7FFFu + ((u >> 16) & 1u)) >> 16);
}
__device__ __forceinline__ float bflo(unsigned p) { return __uint_as_float(p << 16); }
__device__ __forceinline__ float bfhi(unsigned p) { return __uint_as_float(p & 0xFFFF0000u); }
__device__ __forceinline__ float ld_f(const void* p, int i, bool bf16) {
    if (bf16) {
        unsigned h = ((const unsigned short*)p)[i];
        return __uint_as_float(h << 16);
    }
    return ((const float*)p)[i];
}
__device__ __forceinline__ short8 ld_frag(const void* p, size_t off, bool bf16) {
    if (bf16) return *(const short8*)((const short*)p + off);
    const float* f = (const float*)p + off;
    f32x4 f0 = *(const f32x4*)f;
    f32x4 f1 = *(const f32x4*)(f + 4);
    short8 r;
    r[0] = f2bf(f0[0]); r[1] = f2bf(f0[1]); r[2] = f2bf(f0[2]); r[3] = f2bf(f0[3]);
    r[4] = f2bf(f1[0]); r[5] = f2bf(f1[1]); r[6] = f2bf(f1[2]); r[7] = f2bf(f1[3]);
    return r;
}
__device__ __forceinline__ float escore(float ss, float st) {
    float v = ss + st;
    v = v > 0.f ? v : NEG * v;                // leaky relu
    return __expf(fminf(v, 60.f));            // shift-free softmax numerator
}
// Per-wave dtype probes. All 64 lanes active when called.
__device__ __forceinline__ bool wave_bf16(const unsigned* x32) {
    unsigned w  = x32[threadIdx.x & 63];
    unsigned ex = (w >> 7) & 0xFFu;           // bf16 exponent of x[2*lane] if packed
    return __popcll(__ballot(ex >= 118u && ex <= 130u)) >= 48;
}
__device__ __forceinline__ bool wave_e64(const int* e32) {
    return __popcll(__ballot(e32[2 * (threadIdx.x & 63) + 1] == 0)) == 64;
}

// Kernel 1 (fused): blocks [0,projBlocks) = the two GEMMs (proj->bf16 + fused
// head scores; skip->bf16). Blocks [projBlocks, projBlocks+HB) = per-block
// 16-bit packed LDS histogram of tgt (per-block bin count <= perB=5000 < 2^16),
// written non-atomically to hist2d[b][*].
__global__ __launch_bounds__(256) void k_projhist(
    const void* __restrict__ x, const void* __restrict__ Wp,
    const void* __restrict__ Ws,
    const void* __restrict__ ssrcw, const void* __restrict__ stgtw,
    unsigned short* __restrict__ projb, unsigned short* __restrict__ skipb,
    float* __restrict__ s_src, float* __restrict__ s_tgt,
    const int* __restrict__ e32, int* __restrict__ hist2d,
    int N, int E, int tiles, int halfTiles, int projBlocks, int perB)
{
    __shared__ unsigned l32[NMAX / 2];        // 20 KB: two 16-bit bins per word
    if ((int)blockIdx.x >= projBlocks) {
        // ---- LDS histogram role (no global atomics) ----
        const bool e64 = wave_e64(e32);
        const int hb = (int)blockIdx.x - projBlocks;
        const int t = threadIdx.x;
        const int nw = (N + 1) >> 1;
        for (int j = t; j < nw; j += 256) l32[j] = 0;
        __syncthreads();
        const int lo = hb * perB;
        const int hi = min(lo + perB, E);
        for (int i = lo + t; i < hi; i += 256) {
            int tg = e64 ? e32[2 * ((size_t)E + i)] : e32[(size_t)E + i];
            atomicAdd(&l32[tg >> 1], 1u << ((tg & 1) << 4));   // LDS atomic
        }
        __syncthreads();
        for (int j = t; j < N; j += 256)
            hist2d[(size_t)hb * N + j] = (l32[j >> 1] >> ((j & 1) << 4)) & 0xFFFFu;
        return;
    }
    // ---- GEMM role ----
    const bool bf16 = wave_bf16((const unsigned*)x);
    const int lane = threadIdx.x & 63;
    const int wt = blockIdx.x * 4 + (threadIdx.x >> 6);
    if (wt >= tiles) return;
    const int mat = (wt >= halfTiles) ? 1 : 0;
    const int m0 = (mat ? wt - halfTiles : wt) * 16;
    const int mr = lane & 15;
    const int kb = lane >> 4;

    short8 a[4];
    const size_t xoff = (size_t)(m0 + mr) * FIN + kb * 8;
#pragma unroll
    for (int s = 0; s < 4; ++s) a[s] = ld_frag(x, xoff + s * 32, bf16);

    const void* W = mat ? Ws : Wp;
    f32x4 acc[8];
#pragma unroll
    for (int c = 0; c < 8; ++c) {
        acc[c] = (f32x4){0.f, 0.f, 0.f, 0.f};
        const size_t woff = (size_t)(c * 16 + mr) * FIN + kb * 8;
#pragma unroll
        for (int s = 0; s < 4; ++s) {
            short8 b = ld_frag(W, woff + s * 32, bf16);
            acc[c] = __builtin_amdgcn_mfma_f32_16x16x32_bf16(a[s], b, acc[c], 0, 0, 0);
        }
    }
    // D layout: col = lane&15, row = (lane>>4)*4 + r   [verified m89]
    if (mat == 0) {
#pragma unroll
        for (int c = 0; c < 8; ++c) {
            float sw = ld_f(ssrcw, c * 16 + mr, bf16);
            float tw = ld_f(stgtw, c * 16 + mr, bf16);
#pragma unroll
            for (int r = 0; r < 4; ++r) {
                int row = m0 + kb * 4 + r;
                float v = acc[c][r];
                projb[(size_t)row * FIN + c * 16 + mr] = (unsigned short)f2bf(v);
                float vs = v * sw, vt = v * tw;
#pragma unroll
                for (int o = 8; o >= 1; o >>= 1) {
                    vs += __shfl_xor(vs, o);
                    vt += __shfl_xor(vt, o);
                }
                if (mr == 0) {
                    s_src[row * NH + c] = vs;
                    s_tgt[row * NH + c] = vt;
                }
            }
        }
    } else {
#pragma unroll
        for (int c = 0; c < 8; ++c)
#pragma unroll
            for (int r = 0; r < 4; ++r)
                skipb[(size_t)(m0 + kb * 4 + r) * FIN + c * 16 + mr] =
                    (unsigned short)f2bf(acc[c][r]);
    }
}

// Kernel 2: per-bin exclusive prefix across the HB block-rows (coalesced:
// thread <-> bin). pbase[b][j] = sum_{b'<b} hist2d[b'][j]; cnt[j] = total.
__global__ __launch_bounds__(256) void k_colscan(
    const int* __restrict__ hist2d, int* __restrict__ pbase,
    int* __restrict__ cnt, int N)
{
    int j = blockIdx.x * 256 + threadIdx.x;
    if (j >= N) return;
    int s = 0;
#pragma unroll 4
    for (int b = 0; b < HB; ++b) {
        int v = hist2d[(size_t)b * N + j];
        pbase[(size_t)b * N + j] = s;
        s += v;
    }
    cnt[j] = s;
}

// Kernel 3: single-block exclusive scan of cnt -> offs.
__global__ __launch_bounds__(256) void k_offscan(const int* __restrict__ cnt,
                                                 int* __restrict__ offs, int N)
{
    const int t = threadIdx.x;
    const int PER = (N + 255) / 256;          // 40 for N=10000
    const int base = t * PER;
    int local[40];
    int sum = 0;
    for (int i = 0; i < PER && i < 40; ++i) {
        int idx = base + i;
        int v = (idx < N) ? cnt[idx] : 0;
        local[i] = sum;
        sum += v;
    }
    __shared__ int sd[256];
    sd[t] = sum;
    __syncthreads();
#pragma unroll
    for (int off = 1; off < 256; off <<= 1) {
        int add = (t >= off) ? sd[t - off] : 0;
        __syncthreads();
        sd[t] += add;
        __syncthreads();
    }
    int excl = sd[t] - sum;
    for (int i = 0; i < PER && i < 40; ++i) {
        int idx = base + i;
        if (idx < N) offs[idx] = excl + local[i];
    }
    if (t == 255) offs[N] = sd[255];
}

// Kernel 4: placement. Block b re-reads its edge slice; LDS cursor seeded from
// offs+pbase; rank via LDS atomicAdd; one scattered 4B store per edge.
// Zero global atomics.
__global__ __launch_bounds__(256) void k_place(
    const int* __restrict__ e32, const int* __restrict__ offs,
    const int* __restrict__ pbase, int* __restrict__ sorted_src,
    int N, int E, int perB)
{
    __shared__ int cur[NMAX];
    const bool e64 = wave_e64(e32);
    const int b = blockIdx.x, t = threadIdx.x;
    for (int j = t; j < N; j += 256)
        cur[j] = offs[j] + pbase[(size_t)b * N + j];
    __syncthreads();
    const int lo = b * perB;
    const int hi = min(lo + perB, E);
    for (int i = lo + t; i < hi; i += 256) {
        int s, tg;
        if (e64) { s = e32[2 * (size_t)i]; tg = e32[2 * ((size_t)E + i)]; }
        else     { s = e32[i];             tg = e32[(size_t)E + i]; }
        int pos = atomicAdd(&cur[tg], 1);  // LDS atomic
        sorted_src[pos] = s;
    }
}

// Kernel 5: one WAVE per node. Lane l owns column pair (2l, 2l+1) — both in
// head l>>3 — gathered as ONE packed bf16x2 4B load per edge. Numerator and
// denominator accumulate in registers; skip+bias epilogue. 4-way unroll.
__global__ __launch_bounds__(64) void k_aggregate(
    const int* __restrict__ offs, const int* __restrict__ sorted_src,
    const float* __restrict__ s_src, const float* __restrict__ s_tgt,
    const unsigned short* __restrict__ projb, const unsigned short* __restrict__ skipb,
    const void* __restrict__ bias, void* __restrict__ out,
    const unsigned* __restrict__ x32)
{
    const bool bf16 = wave_bf16(x32);
    const int n = blockIdx.x, l = threadIdx.x;
    const int start = offs[n], end = offs[n + 1];
    const int h = l >> 3;
    const int c2 = l * 2;
    const float st = s_tgt[(size_t)n * NH + h];

    float ae0 = 0.f, ao0 = 0.f, ae1 = 0.f, ao1 = 0.f;
    float ae2 = 0.f, ao2 = 0.f, ae3 = 0.f, ao3 = 0.f;
    float d0 = 0.f, d1 = 0.f, d2 = 0.f, d3 = 0.f;
    int e = start;
    for (; e + 4 <= end; e += 4) {
        int s0 = sorted_src[e],     s1 = sorted_src[e + 1];
        int s2 = sorted_src[e + 2], s3 = sorted_src[e + 3];
        float w0 = escore(s_src[(size_t)s0 * NH + h], st);
        float w1 = escore(s_src[(size_t)s1 * NH + h], st);
        float w2 = escore(s_src[(size_t)s2 * NH + h], st);
        float w3 = escore(s_src[(size_t)s3 * NH + h], st);
        unsigned p0 = *(const unsigned*)(projb + (size_t)s0 * FIN + c2);
        unsigned p1 = *(const unsigned*)(projb + (size_t)s1 * FIN + c2);
        unsigned p2 = *(const unsigned*)(projb + (size_t)s2 * FIN + c2);
        unsigned p3 = *(const unsigned*)(projb + (size_t)s3 * FIN + c2);
        ae0 += w0 * bflo(p0); ao0 += w0 * bfhi(p0); d0 += w0;
        ae1 += w1 * bflo(p1); ao1 += w1 * bfhi(p1); d1 += w1;
        ae2 += w2 * bflo(p2); ao2 += w2 * bfhi(p2); d2 += w2;
        ae3 += w3 * bflo(p3); ao3 += w3 * bfhi(p3); d3 += w3;
    }
    for (; e < end; ++e) {
        int s = sorted_src[e];
        float w = escore(s_src[(size_t)s * NH + h], st);
        unsigned p = *(const unsigned*)(projb + (size_t)s * FIN + c2);
        ae0 += w * bflo(p); ao0 += w * bfhi(p); d0 += w;
    }

    float inv = 1.f / (((d0 + d1) + (d2 + d3)) + 1e-16f);
    unsigned skp = *(const unsigned*)(skipb + (size_t)n * FIN + c2);
    float be, bo;
    if (bf16) {
        unsigned bb = *(const unsigned*)((const unsigned short*)bias + c2);
        be = bflo(bb); bo = bfhi(bb);
    } else {
        float2 b2 = *(const float2*)((const float*)bias + c2);
        be = b2.x; bo = b2.y;
    }
    float oe = ((ae0 + ae1) + (ae2 + ae3)) * inv + bflo(skp) + be;
    float oo = ((ao0 + ao1) + (ao2 + ao3)) * inv + bfhi(skp) + bo;
    if (bf16) {
        unsigned pr = ((unsigned)(unsigned short)f2bf(oo) << 16)
                    | (unsigned)(unsigned short)f2bf(oe);
        ((unsigned*)out)[((size_t)n * FIN + c2) >> 1] = pr;
    } else {
        float2 o2; o2.x = oe; o2.y = oo;
        *(float2*)((float*)out + (size_t)n * FIN + c2) = o2;
    }
}

extern "C" void kernel_launch(void* const* d_in, const int* in_sizes, int n_in,
                              void* d_out, int out_size, void* d_ws, size_t ws_size,
                              hipStream_t stream)
{
    const void* x    = d_in[0];
    const int* edges = (const int*)d_in[1];
    const void* Wp   = d_in[2];
    const void* Ws   = d_in[3];
    const void* ssw  = d_in[4];
    const void* stw  = d_in[5];
    const void* bias = d_in[6];

    const int N = in_sizes[0] / FIN;   // 10000
    const int E = in_sizes[1] / 2;     // 640000

    // workspace layout
    unsigned short* projb = (unsigned short*)d_ws;            // N*128 bf16
    unsigned short* skipb = projb + (size_t)N * FIN;          // N*128 bf16
    float* s_src    = (float*)(skipb + (size_t)N * FIN);      // N*8
    float* s_tgt    = s_src + (size_t)N * NH;                 // N*8
    int* sorted_src = (int*)(s_tgt + (size_t)N * NH);         // E
    int* offs       = sorted_src + E;                         // N+1
    int* cnt        = offs + (N + 1);                         // N
    int* hist2d     = cnt + N;                                // HB*N
    int* pbase      = hist2d + (size_t)HB * N;                // HB*N

    const int halfTiles  = (N + 15) / 16;        // 625
    const int tiles      = 2 * halfTiles;        // 1250
    const int projBlocks = (tiles + 3) / 4;      // 313
    const int perB       = (E + HB - 1) / HB;    // 5000

    k_projhist<<<projBlocks + HB, 256, 0, stream>>>(
        x, Wp, Ws, ssw, stw, projb, skipb, s_src, s_tgt,
        edges, hist2d, N, E, tiles, halfTiles, projBlocks, perB);
    k_colscan<<<(N + 255) / 256, 256, 0, stream>>>(hist2d, pbase, cnt, N);
    k_offscan<<<1, 256, 0, stream>>>(cnt, offs, N);
    k_place<<<HB, 256, 0, stream>>>(edges, offs, pbase, sorted_src, N, E, perB);
    k_aggregate<<<N, 64, 0, stream>>>(offs, sorted_src, s_src, s_tgt, projb,
                                      skipb, bias, d_out, (const unsigned*)x);
}